// Round 9
// baseline (6676.868 us; speedup 1.0000x reference)
//
#include <hip/hip_runtime.h>
#include <cstdio>

typedef __attribute__((ext_vector_type(8))) short short8;
typedef __attribute__((ext_vector_type(4))) float f32x4;
typedef unsigned long long u64;

#define MFMA16(a,b,c) __builtin_amdgcn_mfma_f32_16x16x32_bf16((a),(b),(c),0,0,0)
#define LOAD_SYS(p)    __hip_atomic_load((p), __ATOMIC_RELAXED, __HIP_MEMORY_SCOPE_SYSTEM)
#define STORE_SYS(p,v) __hip_atomic_store((p), (v), __ATOMIC_RELAXED, __HIP_MEMORY_SCOPE_SYSTEM)

// workspace layout (bytes)
constexpr size_t CNT_OFF = 0;                            // 5 * 1KB flag regions (real + 4 ablations)
constexpr size_t HB_OFF  = 8192;                         // 2 bufs * 8 groups * 64KB = 1MB
constexpr size_t PK1_OFF = HB_OFF + 2ul * 8 * 65536;     // Wh1 pack, 2MB
constexpr size_t PK2_OFF = PK1_OFF + 2097152;            // Wh2 pack, 2MB
constexpr size_t PKX_OFF = PK2_OFF + 2097152;            // Wx2 pack, 2MB
constexpr size_t SEQ_OFF = PKX_OFF + 2097152;            // seq1 pack: 8 * 200 * 64KB (~105MB)
constexpr size_t WS_NEED = SEQ_OFF + 8ul * 200 * 65536;  // ~112 MB

__device__ __forceinline__ short f2bf(float f) {
  union { float f; unsigned u; } v; v.f = f;
  unsigned r = v.u + 0x7fffu + ((v.u >> 16) & 1u);
  return (short)(r >> 16);
}
__device__ __forceinline__ float bf2f(short s) {
  union { float f; unsigned u; } v; v.u = ((unsigned)(unsigned short)s) << 16;
  return v.f;
}
__device__ __forceinline__ float sigm(float x)   { return 1.f / (1.f + __expf(-x)); }
__device__ __forceinline__ float tanh_f(float x) { return 1.f - 2.f / (1.f + __expf(2.f * x)); }

// Pack W[512][2048] fp32 (row-major, K x N) into MFMA B-fragment order:
// frag (nf,kf): lane l holds B[k = kf*32 + (l>>4)*8 + e][n = nf*16 + (l&15)], e=0..7
__global__ void pack_w(const float* __restrict__ wh1, const float* __restrict__ wh2,
                       const float* __restrict__ wx2, unsigned char* __restrict__ ws)
{
  int tid = blockIdx.x * 256 + threadIdx.x;   // 3 * 65536 threads
  int m   = tid >> 16;
  int rem = tid & 65535;
  int k   = rem >> 7;     // 0..511
  int nf  = rem & 127;    // 0..127
  const float* W = (m == 0) ? wh1 : (m == 1) ? wh2 : wx2;
  short* dst = (short*)(ws + ((m == 0) ? PK1_OFF : (m == 1) ? PK2_OFF : PKX_OFF));
  int kf = k >> 5, sub = (k >> 3) & 3, e = k & 7;
  int base = ((nf * 16 + kf) * 64 + sub * 16) * 8 + e;
  const float* src = W + (size_t)k * 2048 + nf * 16;
#pragma unroll
  for (int c = 0; c < 16; ++c) dst[base + c * 8] = f2bf(src[c]);
}

// ---------------- ablation kernels (diagnosis; write only hb + own flags) ----------------
// MODE 0 = full protocol (phase-1-like step)   [in-launch baseline]
// MODE 1 = no flag-wait                        [dur delta = sync/skew cost]
// MODE 2 = no h-loads (MFMA on stale regs)     [dur delta = h-load cost]
// MODE 3 = no MFMA/gates (loads kept via sink) [dur delta = compute cost]
template<int MODE>
__global__ __launch_bounds__(256, 1) void lstm_ablate(unsigned char* __restrict__ ws)
{
  __shared__ short8 bwh[64][64];
  __shared__ unsigned short htile[64][20];

  const int tid  = threadIdx.x;
  const int blk  = blockIdx.x;
  const int gr   = blk & 7;
  const int wj   = blk >> 3;
  const int w    = tid >> 6;
  const int lane = tid & 63;

  unsigned* fl = (unsigned*)(ws + CNT_OFF) + (size_t)(1 + MODE) * 256 + gr * 32;
  short8* hb0 = (short8*)(ws + HB_OFF) + (size_t)(0 * 8 + gr) * 4096;
  short8* hb1 = (short8*)(ws + HB_OFF) + (size_t)(1 * 8 + gr) * 4096;
  const short8* pk1 = (const short8*)(ws + PK1_OFF);

#pragma unroll
  for (int i = 0; i < 16; ++i) {
    int f = (i << 2) | w;
    bwh[f][lane] = pk1[(((f >> 4) * 32 + wj) * 16 + (f & 15)) * 64 + lane];
  }
  __syncthreads();

  const int rbase = w * 16 + ((lane >> 4) << 2);
  const int lc = lane & 15;
  const int rr  = tid >> 2, run = tid & 3;
  const int jc0 = wj * 16 + run * 4;
  const int bidx = ((((jc0 >> 5) * 4 + (rr >> 4)) * 64 + ((jc0 >> 3) & 3) * 16 + (rr & 15)) * 8
                    + (jc0 & 7)) >> 2;

  float cst[4] = {0.f, 0.f, 0.f, 0.f};
  short8 afr[16];
  if (MODE == 2) {           // stale but live registers for the MFMAs
#pragma unroll
    for (int kf = 0; kf < 16; ++kf) afr[kf] = bwh[kf][lane];
  }

#pragma unroll 1
  for (int t = 0; t < 400; ++t) {
    f32x4 acc[4];
#pragma unroll
    for (int G = 0; G < 4; ++G) {                 // loop-variant init: prevents MFMA hoisting
      f32x4 z = {(float)t, 0.f, 0.f, 0.f}; acc[G] = z;
    }

    if (t > 0) {
      if (MODE == 1) {
        if (tid < 64) {
          unsigned v = LOAD_SYS((unsigned*)&fl[tid & 31]);
          asm volatile("" :: "v"(v));             // keep the load, no spin
        }
      } else {
        if (tid < 64) {
          const unsigned* fp = &fl[tid & 31];
          while (1) {
            unsigned v = LOAD_SYS((unsigned*)fp);
            if (__all((int)(v >= (unsigned)t))) break;
            __builtin_amdgcn_s_sleep(1);
          }
          asm volatile("" ::: "memory");
        }
      }
      __syncthreads();

      const short8* hsrc = (t & 1) ? hb0 : hb1;
      if (MODE != 2) {
#pragma unroll
        for (int kf = 0; kf < 16; ++kf)
          asm volatile("global_load_dwordx4 %0, %1, off sc0 sc1"
                       : "=&v"(afr[kf]) : "v"(hsrc + (kf * 4 + w) * 64 + lane));
        asm volatile("s_waitcnt vmcnt(0)" ::: "memory");
        __builtin_amdgcn_sched_barrier(0);
      }
      if (MODE == 3) {
#pragma unroll
        for (int kf = 0; kf < 16; ++kf) asm volatile("" :: "v"(afr[kf]));   // keep loads live
      } else {
#pragma unroll
        for (int kf = 0; kf < 16; ++kf) {
#pragma unroll
          for (int G = 0; G < 4; ++G)
            acc[G] = MFMA16(afr[kf], bwh[(G << 4) | kf][lane], acc[G]);
        }
      }
    }

    if (MODE != 3) {
#pragma unroll
      for (int r = 0; r < 4; ++r) {
        float ig = sigm(acc[0][r] + 0.5f);
        float fg = sigm(acc[1][r] + 0.5f);
        float gg = tanh_f(acc[2][r] + 0.5f);
        float og = sigm(acc[3][r] + 0.5f);
        float cc = fg * cst[r] + ig * gg;
        cst[r] = cc;
        htile[rbase + r][lc] = (unsigned short)f2bf(og * tanh_f(cc));
      }
    } else {
#pragma unroll
      for (int r = 0; r < 4; ++r)
        htile[rbase + r][lc] = (unsigned short)(t + tid + r);
    }
    __syncthreads();

    {
      u64 hv = *(const u64*)&htile[rr][run * 4];
      short8* dst = (t & 1) ? hb1 : hb0;
      STORE_SYS((u64*)dst + bidx, hv);
    }
    __syncthreads();
    if (tid == 0)
      STORE_SYS(&fl[wj], (unsigned)(t + 1));
  }
}

// ---------------- real kernel: exact R7 configuration (best verified: 2027 us) ----------------
__global__ __launch_bounds__(256, 1) void lstm_main(
    const float* __restrict__ inp, const float* __restrict__ Wx1,
    const float* __restrict__ b1,  const float* __restrict__ b2,
    const float* __restrict__ Wfc, const float* __restrict__ bfc,
    unsigned char* __restrict__ ws, float* __restrict__ out)
{
  __shared__ short8 bwh[64][64];             // Wh chunk of current layer, 64 KB
  __shared__ short8 bwx[64][64];             // Wx2 chunk, 64 KB
  __shared__ unsigned short htile[64][20];   // h transpose staging (padded), 2.5 KB
  __shared__ float red[256];

  const int tid  = threadIdx.x;
  const int blk  = blockIdx.x;
  const int gr   = blk & 7;     // row-group
  const int wj   = blk >> 3;    // 0..31: owns h-cols [wj*16, wj*16+16)
  const int w    = tid >> 6;    // wave 0..3: owns rows [w*16, w*16+16) of group
  const int lane = tid & 63;

  unsigned* fl = (unsigned*)(ws + CNT_OFF) + gr * 32;   // region 0
  short8* hb0 = (short8*)(ws + HB_OFF) + (size_t)(0 * 8 + gr) * 4096;
  short8* hb1 = (short8*)(ws + HB_OFF) + (size_t)(1 * 8 + gr) * 4096;
  const short8* pk1 = (const short8*)(ws + PK1_OFF);
  const short8* pk2 = (const short8*)(ws + PK2_OFF);
  const short8* pkx = (const short8*)(ws + PKX_OFF);
  short8* seq = (short8*)(ws + SEQ_OFF) + (size_t)gr * (200 * 4096);

  // Wh1 + Wx2 chunks -> LDS (f encodes (G = f>>4, kf = f&15))
#pragma unroll
  for (int i = 0; i < 16; ++i) {
    int f = (i << 2) | w;
    bwh[f][lane] = pk1[(((f >> 4) * 32 + wj) * 16 + (f & 15)) * 64 + lane];
    bwx[f][lane] = pkx[(((f >> 4) * 32 + wj) * 16 + (f & 15)) * 64 + lane];
  }
  __syncthreads();

  // per-thread gate constants: this thread's z-column j
  const int jcol = wj * 16 + (lane & 15);
  float wx1v[4], b1v[4], b2v[4];
#pragma unroll
  for (int G = 0; G < 4; ++G) {
    wx1v[G] = Wx1[G * 512 + jcol];
    b1v[G]  = b1[G * 512 + jcol];
    b2v[G]  = b2[G * 512 + jcol];
  }

  const int rbase = w * 16 + ((lane >> 4) << 2);                // row-in-group base (4 rows)
  const float* xptr = inp + (size_t)(gr * 64 + rbase) * 200;
  const int lc = lane & 15;                                     // local h-col 0..15

  // pack-phase addressing (thread -> (row rr, 4 consecutive cols))
  const int rr  = tid >> 2, run = tid & 3;
  const int jc0 = wj * 16 + run * 4;
  const int bidx = ((((jc0 >> 5) * 4 + (rr >> 4)) * 64 + ((jc0 >> 3) & 3) * 16 + (rr & 15)) * 8
                    + (jc0 & 7)) >> 2;   // u64 index into A-frag pack

  float cst[4] = {0.f, 0.f, 0.f, 0.f};

#pragma unroll 1
  for (int t = 0; t < 400; ++t) {
    // ---- prefetch this step's x values (independent of h) ----
    float xv[4];
    if (t < 200) {
#pragma unroll
      for (int r = 0; r < 4; ++r) xv[r] = xptr[r * 200 + t];
    }

    f32x4 acc[4];
#pragma unroll
    for (int G = 0; G < 4; ++G) { f32x4 z = {0.f, 0.f, 0.f, 0.f}; acc[G] = z; }

    // ---- x-projection (t>=200, reads write-once seq[t-200], plain cached) ----
    if (t >= 200) {
      const short8* sp = seq + (size_t)(t - 200) * 4096;
#pragma unroll
      for (int kf = 0; kf < 16; ++kf) {
        short8 sa = sp[(kf * 4 + w) * 64 + lane];
#pragma unroll
        for (int G = 0; G < 4; ++G)
          acc[G] = MFMA16(sa, bwx[(G << 4) | kf][lane], acc[G]);
      }
    }

    if (t > 0) {
      // ---- wait: all 32 WGs of this group completed step t-1 (flag >= t) ----
      if (tid < 64) {
        const unsigned* fp = &fl[tid & 31];
        while (1) {
          unsigned v = LOAD_SYS((unsigned*)fp);
          if (__all((int)(v >= (unsigned)t))) break;
          __builtin_amdgcn_s_sleep(1);
        }
        asm volatile("" ::: "memory");
      }
      __syncthreads();

      // ---- recurrent part: h_{t-1} via batched LLC loads, then MFMA from LDS weights ----
      const short8* hsrc = (t <= 200) ? (seq + (size_t)(t - 1) * 4096)
                                      : ((t & 1) ? hb0 : hb1);
      short8 afr[16];
#pragma unroll
      for (int kf = 0; kf < 16; ++kf)
        asm volatile("global_load_dwordx4 %0, %1, off sc0 sc1"
                     : "=&v"(afr[kf]) : "v"(hsrc + (kf * 4 + w) * 64 + lane));
      asm volatile("s_waitcnt vmcnt(0)" ::: "memory");
      __builtin_amdgcn_sched_barrier(0);
#pragma unroll
      for (int kf = 0; kf < 16; ++kf) {
#pragma unroll
        for (int G = 0; G < 4; ++G) {
          short8 bb = bwh[(G << 4) | kf][lane];
          acc[G] = MFMA16(afr[kf], bb, acc[G]);
        }
      }
    }

    // ---- gates + state update -> LDS transpose tile ----
#pragma unroll
    for (int r = 0; r < 4; ++r) {
      float a0, a1, a2, a3;
      if (t < 200) {
        a0 = fmaf(xv[r], wx1v[0], b1v[0]);
        a1 = fmaf(xv[r], wx1v[1], b1v[1]);
        a2 = fmaf(xv[r], wx1v[2], b1v[2]);
        a3 = fmaf(xv[r], wx1v[3], b1v[3]);
      } else {
        a0 = b2v[0]; a1 = b2v[1]; a2 = b2v[2]; a3 = b2v[3];
      }
      float ig = sigm(acc[0][r] + a0);
      float fg = sigm(acc[1][r] + a1);
      float gg = tanh_f(acc[2][r] + a2);
      float og = sigm(acc[3][r] + a3);
      float cc = fg * cst[r] + ig * gg;
      cst[r] = cc;
      htile[rbase + r][lc] = (unsigned short)f2bf(og * tanh_f(cc));
    }
    __syncthreads();

    // ---- pack 4 consecutive cols of one row -> ONE 8B store ----
    {
      u64 hv = *(const u64*)&htile[rr][run * 4];
      short8* dst = (t < 200) ? (seq + (size_t)t * 4096)
                              : ((t & 1) ? hb1 : hb0);
      STORE_SYS((u64*)dst + bidx, hv);
    }
    __syncthreads();   // drains vmcnt(0) before s_barrier: stores acked before post
    if (tid == 0)
      STORE_SYS(&fl[wj], (unsigned)(t + 1));

    if (t == 199) {    // swap recurrent weights to layer 2 (reads resume at t=200)
#pragma unroll
      for (int i = 0; i < 16; ++i) {
        int f = (i << 2) | w;
        bwh[f][lane] = pk2[(((f >> 4) * 32 + wj) * 16 + (f & 15)) * 64 + lane];
      }
    }
  }

  // final FC: logits = h2_final @ Wfc + bfc   (t=399 wrote hb1)
  if (wj == 0) {
    if (tid < 64) {
      const unsigned* fp = &fl[tid & 31];
      while (1) {
        unsigned v = LOAD_SYS((unsigned*)fp);
        if (__all((int)(v >= 400u))) break;
        __builtin_amdgcn_s_sleep(1);
      }
      asm volatile("" ::: "memory");
    }
    __syncthreads();

    const u64* h2 = (const u64*)hb1;
    int r = tid >> 2, q = tid & 3;
    float s = 0.f;
    for (int c = 0; c < 16; ++c) {
      int k0 = q * 128 + c * 8;
      int bi = ((((k0 >> 5) * 4 + (r >> 4)) * 64 + ((k0 >> 3) & 3) * 16 + (r & 15)) * 8) >> 2;
      union { u64 u[2]; unsigned short ss[8]; } cv;
      cv.u[0] = LOAD_SYS((u64*)h2 + bi);
      cv.u[1] = LOAD_SYS((u64*)h2 + bi + 1);
#pragma unroll
      for (int e = 0; e < 8; ++e)
        s = fmaf(bf2f((short)cv.ss[e]), Wfc[k0 + e], s);
    }
    red[tid] = s;
    __syncthreads();
    if (q == 0)
      out[gr * 64 + r] = red[tid] + red[tid + 1] + red[tid + 2] + red[tid + 3] + bfc[0];
  }
}

extern "C" void kernel_launch(void* const* d_in, const int* in_sizes, int n_in,
                              void* d_out, int out_size, void* d_ws, size_t ws_size,
                              hipStream_t stream)
{
  if (ws_size < WS_NEED) {
    fprintf(stderr, "kernel_launch: ws_size %zu < needed %zu\n", ws_size, WS_NEED);
    return;
  }
  const float* inp = (const float*)d_in[0];
  const float* Wx1 = (const float*)d_in[1];
  const float* Wh1 = (const float*)d_in[2];
  const float* b1  = (const float*)d_in[3];
  const float* Wx2 = (const float*)d_in[4];
  const float* Wh2 = (const float*)d_in[5];
  const float* b2  = (const float*)d_in[6];
  const float* Wfc = (const float*)d_in[7];
  const float* bfc = (const float*)d_in[8];
  unsigned char* ws = (unsigned char*)d_ws;

  hipMemsetAsync(ws, 0, 8192, stream);                        // all flag regions
  pack_w<<<768, 256, 0, stream>>>(Wh1, Wh2, Wx2, ws);
  lstm_ablate<0><<<256, 256, 0, stream>>>(ws);                // abA: full protocol
  lstm_ablate<1><<<256, 256, 0, stream>>>(ws);                // abB: no wait
  lstm_ablate<2><<<256, 256, 0, stream>>>(ws);                // abC: no h-load
  lstm_ablate<3><<<256, 256, 0, stream>>>(ws);                // abD: no compute
  lstm_main<<<256, 256, 0, stream>>>(inp, Wx1, b1, b2, Wfc, bfc, ws, (float*)d_out);
}

// Round 10
// 1694.889 us; speedup vs baseline: 3.9394x; 3.9394x over previous
//
#include <hip/hip_runtime.h>
#include <cstdio>

typedef __attribute__((ext_vector_type(8))) short short8;
typedef __attribute__((ext_vector_type(4))) float f32x4;
typedef unsigned long long u64;

#define MFMA16(a,b,c) __builtin_amdgcn_mfma_f32_16x16x32_bf16((a),(b),(c),0,0,0)
#define LOAD_SYS(p)    __hip_atomic_load((p), __ATOMIC_RELAXED, __HIP_MEMORY_SCOPE_SYSTEM)
#define STORE_SYS(p,v) __hip_atomic_store((p), (v), __ATOMIC_RELAXED, __HIP_MEMORY_SCOPE_SYSTEM)

// workspace layout (bytes)
constexpr size_t CNT_OFF = 0;                            // 8 groups * 32 flag words (128B lines)
constexpr size_t HB_OFF  = 8192;                         // 2 bufs * 8 groups * 64KB = 1MB (h2 dbuf)
constexpr size_t PK1_OFF = HB_OFF + 2ul * 8 * 65536;     // Wh1 pack, 2MB
constexpr size_t PK2_OFF = PK1_OFF + 2097152;            // Wh2 pack, 2MB
constexpr size_t PKX_OFF = PK2_OFF + 2097152;            // Wx2 pack, 2MB
constexpr size_t SEQ_OFF = PKX_OFF + 2097152;            // seq1 pack: 8 * 200 * 64KB (~105MB)
constexpr size_t WS_NEED = SEQ_OFF + 8ul * 200 * 65536;  // ~112 MB

__device__ __forceinline__ short f2bf(float f) {
  union { float f; unsigned u; } v; v.f = f;
  unsigned r = v.u + 0x7fffu + ((v.u >> 16) & 1u);
  return (short)(r >> 16);
}
__device__ __forceinline__ float bf2f(short s) {
  union { float f; unsigned u; } v; v.u = ((unsigned)(unsigned short)s) << 16;
  return v.f;
}
__device__ __forceinline__ float sigm(float x)   { return 1.f / (1.f + __expf(-x)); }
__device__ __forceinline__ float tanh_f(float x) { return 1.f - 2.f / (1.f + __expf(2.f * x)); }

// Pack W[512][2048] fp32 (row-major, K x N) into MFMA B-fragment order:
// frag (nf,kf): lane l holds B[k = kf*32 + (l>>4)*8 + e][n = nf*16 + (l&15)], e=0..7
__global__ void pack_w(const float* __restrict__ wh1, const float* __restrict__ wh2,
                       const float* __restrict__ wx2, unsigned char* __restrict__ ws)
{
  int tid = blockIdx.x * 256 + threadIdx.x;   // 3 * 65536 threads
  int m   = tid >> 16;
  int rem = tid & 65535;
  int k   = rem >> 7;     // 0..511
  int nf  = rem & 127;    // 0..127
  const float* W = (m == 0) ? wh1 : (m == 1) ? wh2 : wx2;
  short* dst = (short*)(ws + ((m == 0) ? PK1_OFF : (m == 1) ? PK2_OFF : PKX_OFF));
  int kf = k >> 5, sub = (k >> 3) & 3, e = k & 7;
  int base = ((nf * 16 + kf) * 64 + sub * 16) * 8 + e;
  const float* src = W + (size_t)k * 2048 + nf * 16;
#pragma unroll
  for (int c = 0; c < 16; ++c) dst[base + c * 8] = f2bf(src[c]);
}

// Diagonal-fused kernel: super-step s runs layer-1 step s AND layer-2 step s-1.
// Both consume the SAME seq[s-1] broadcast tile (loaded once). Wx2 in VGPRs.
__global__ __launch_bounds__(256, 1) void lstm_main(
    const float* __restrict__ inp, const float* __restrict__ Wx1,
    const float* __restrict__ b1,  const float* __restrict__ b2,
    const float* __restrict__ Wfc, const float* __restrict__ bfc,
    unsigned char* __restrict__ ws, float* __restrict__ out)
{
  __shared__ short8 bwh1[64][64];            // Wh1 chunk, 64 KB
  __shared__ short8 bwh2[64][64];            // Wh2 chunk, 64 KB
  __shared__ unsigned short htile1[64][20];  // h1 transpose staging, 2.5 KB
  __shared__ unsigned short htile2[64][20];  // h2 transpose staging, 2.5 KB
  __shared__ float red[256];

  const int tid  = threadIdx.x;
  const int blk  = blockIdx.x;
  const int gr   = blk & 7;     // row-group
  const int wj   = blk >> 3;    // 0..31: owns h-cols [wj*16, wj*16+16)
  const int w    = tid >> 6;    // wave 0..3: owns rows [w*16, w*16+16) of group
  const int lane = tid & 63;

  unsigned* fl = (unsigned*)(ws + CNT_OFF) + gr * 32;   // 32 flag words = one 128B line
  short8* hb0 = (short8*)(ws + HB_OFF) + (size_t)(0 * 8 + gr) * 4096;
  short8* hb1 = (short8*)(ws + HB_OFF) + (size_t)(1 * 8 + gr) * 4096;
  const short8* pk1 = (const short8*)(ws + PK1_OFF);
  const short8* pk2 = (const short8*)(ws + PK2_OFF);
  const short8* pkx = (const short8*)(ws + PKX_OFF);
  short8* seq = (short8*)(ws + SEQ_OFF) + (size_t)gr * (200 * 4096);

  // Wh1 + Wh2 chunks -> LDS (f encodes (G = f>>4, kf = f&15))
#pragma unroll
  for (int i = 0; i < 16; ++i) {
    int f = (i << 2) | w;
    bwh1[f][lane] = pk1[(((f >> 4) * 32 + wj) * 16 + (f & 15)) * 64 + lane];
    bwh2[f][lane] = pk2[(((f >> 4) * 32 + wj) * 16 + (f & 15)) * 64 + lane];
  }
  __syncthreads();

  // Wx2 chunk -> REGISTERS (64 frags = 256 VGPRs; 1 wave/SIMD occupancy)
  short8 bx[64];
#pragma unroll
  for (int f = 0; f < 64; ++f)
    bx[f] = pkx[(((f >> 4) * 32 + wj) * 16 + (f & 15)) * 64 + lane];

  // per-thread gate constants: this thread's z-column j
  const int jcol = wj * 16 + (lane & 15);
  float wx1v[4], b1v[4], b2v[4];
#pragma unroll
  for (int G = 0; G < 4; ++G) {
    wx1v[G] = Wx1[G * 512 + jcol];
    b1v[G]  = b1[G * 512 + jcol];
    b2v[G]  = b2[G * 512 + jcol];
  }

  const int rbase = w * 16 + ((lane >> 4) << 2);                // row-in-group base (4 rows)
  const float* xptr = inp + (size_t)(gr * 64 + rbase) * 200;
  const int lc = lane & 15;                                     // local h-col 0..15

  // pack-phase addressing (thread -> (row rr, 4 consecutive cols))
  const int rr  = tid >> 2, run = tid & 3;
  const int jc0 = wj * 16 + run * 4;
  const int bidx = ((((jc0 >> 5) * 4 + (rr >> 4)) * 64 + ((jc0 >> 3) & 3) * 16 + (rr & 15)) * 8
                    + (jc0 & 7)) >> 2;   // u64 index into A-frag pack

  float cst1[4] = {0.f, 0.f, 0.f, 0.f};   // layer-1 c state
  float cst2[4] = {0.f, 0.f, 0.f, 0.f};   // layer-2 c state

#pragma unroll 1
  for (int s = 0; s <= 200; ++s) {
    // prefetch layer-1 x values (independent of all flags)
    float xv[4];
    if (s < 200) {
#pragma unroll
      for (int r = 0; r < 4; ++r) xv[r] = xptr[r * 200 + s];
    }

    f32x4 acc1[4], acc2[4];
#pragma unroll
    for (int G = 0; G < 4; ++G) {
      f32x4 z = {0.f, 0.f, 0.f, 0.f}; acc1[G] = z; acc2[G] = z;
    }

    short8 afr[16];
    if (s > 0) {
      // ---- wait: all 32 WGs of this group completed super s-1 (flag >= s) ----
      if (tid < 64) {
        const unsigned* fp = &fl[tid & 31];
        while (1) {
          unsigned v = LOAD_SYS((unsigned*)fp);
          if (__all((int)(v >= (unsigned)s))) break;
          __builtin_amdgcn_s_sleep(1);
        }
        asm volatile("" ::: "memory");
      }
      __syncthreads();

      // ---- batched broadcast load: seq[s-1] = h1_{s-1} (shared A-tile) ----
      const short8* hsrc = seq + (size_t)(s - 1) * 4096;
#pragma unroll
      for (int kf = 0; kf < 16; ++kf)
        asm volatile("global_load_dwordx4 %0, %1, off sc0 sc1"
                     : "=&v"(afr[kf]) : "v"(hsrc + (kf * 4 + w) * 64 + lane));
      asm volatile("s_waitcnt vmcnt(0)" ::: "memory");
      __builtin_amdgcn_sched_barrier(0);

      // ---- L1 recurrent (s<200) + L2 x-projection: both consume afr ----
      if (s < 200) {
#pragma unroll
        for (int kf = 0; kf < 16; ++kf) {
#pragma unroll
          for (int G = 0; G < 4; ++G) {
            acc1[G] = MFMA16(afr[kf], bwh1[(G << 4) | kf][lane], acc1[G]);
            acc2[G] = MFMA16(afr[kf], bx[(G << 4) | kf], acc2[G]);
          }
        }
      } else {
#pragma unroll
        for (int kf = 0; kf < 16; ++kf) {
#pragma unroll
          for (int G = 0; G < 4; ++G)
            acc2[G] = MFMA16(afr[kf], bx[(G << 4) | kf], acc2[G]);
        }
      }
    }

    // ---- layer-1 gates -> htile1  (s==0: acc1=0 so z = x*Wx1 + b1) ----
    if (s < 200) {
#pragma unroll
      for (int r = 0; r < 4; ++r) {
        float a0 = fmaf(xv[r], wx1v[0], b1v[0]);
        float a1 = fmaf(xv[r], wx1v[1], b1v[1]);
        float a2 = fmaf(xv[r], wx1v[2], b1v[2]);
        float a3 = fmaf(xv[r], wx1v[3], b1v[3]);
        float ig = sigm(acc1[0][r] + a0);
        float fg = sigm(acc1[1][r] + a1);
        float gg = tanh_f(acc1[2][r] + a2);
        float og = sigm(acc1[3][r] + a3);
        float cc = fg * cst1[r] + ig * gg;
        cst1[r] = cc;
        htile1[rbase + r][lc] = (unsigned short)f2bf(og * tanh_f(cc));
      }
    }

    // ---- issue h2_{s-2} broadcast load into afr (regs free after set-1 MFMAs) ----
    if (s >= 2) {
      const short8* hsrc2 = (s & 1) ? hb1 : hb0;   // hb[s&1] holds h2_{s-2}
#pragma unroll
      for (int kf = 0; kf < 16; ++kf)
        asm volatile("global_load_dwordx4 %0, %1, off sc0 sc1"
                     : "=&v"(afr[kf]) : "v"(hsrc2 + (kf * 4 + w) * 64 + lane));
    }

    __syncthreads();   // htile1 complete

    // ---- pack h1_s -> seq[s] (one 8B store) ----
    if (s < 200) {
      u64 hv = *(const u64*)&htile1[rr][run * 4];
      STORE_SYS((u64*)(seq + (size_t)s * 4096) + bidx, hv);
    }

    // ---- L2 recurrent + gates -> htile2 ----
    if (s >= 1) {
      if (s >= 2) {
        asm volatile("s_waitcnt vmcnt(0)" ::: "memory");
        __builtin_amdgcn_sched_barrier(0);
#pragma unroll
        for (int kf = 0; kf < 16; ++kf) {
#pragma unroll
          for (int G = 0; G < 4; ++G)
            acc2[G] = MFMA16(afr[kf], bwh2[(G << 4) | kf][lane], acc2[G]);
        }
      }
#pragma unroll
      for (int r = 0; r < 4; ++r) {
        float ig = sigm(acc2[0][r] + b2v[0]);
        float fg = sigm(acc2[1][r] + b2v[1]);
        float gg = tanh_f(acc2[2][r] + b2v[2]);
        float og = sigm(acc2[3][r] + b2v[3]);
        float cc = fg * cst2[r] + ig * gg;
        cst2[r] = cc;
        htile2[rbase + r][lc] = (unsigned short)f2bf(og * tanh_f(cc));
      }
    }

    __syncthreads();   // htile2 complete

    // ---- pack h2_{s-1} -> hb[(s-1)&1] ----
    if (s >= 1) {
      u64 hv = *(const u64*)&htile2[rr][run * 4];
      short8* dst = (s & 1) ? hb0 : hb1;
      STORE_SYS((u64*)dst + bidx, hv);
    }

    __syncthreads();   // drain all stores (vmcnt(0) before s_barrier)
    if (tid == 0)
      STORE_SYS(&fl[wj], (unsigned)(s + 1));
  }

  // final FC: logits = h2_199 @ Wfc + bfc   (super 200 wrote hb1)
  if (wj == 0) {
    if (tid < 64) {
      const unsigned* fp = &fl[tid & 31];
      while (1) {
        unsigned v = LOAD_SYS((unsigned*)fp);
        if (__all((int)(v >= 201u))) break;
        __builtin_amdgcn_s_sleep(1);
      }
      asm volatile("" ::: "memory");
    }
    __syncthreads();

    const u64* h2 = (const u64*)hb1;
    int r = tid >> 2, q = tid & 3;
    float s = 0.f;
    for (int c = 0; c < 16; ++c) {
      int k0 = q * 128 + c * 8;
      int bi = ((((k0 >> 5) * 4 + (r >> 4)) * 64 + ((k0 >> 3) & 3) * 16 + (r & 15)) * 8) >> 2;
      union { u64 u[2]; unsigned short ss[8]; } cv;
      cv.u[0] = LOAD_SYS((u64*)h2 + bi);
      cv.u[1] = LOAD_SYS((u64*)h2 + bi + 1);
#pragma unroll
      for (int e = 0; e < 8; ++e)
        s = fmaf(bf2f((short)cv.ss[e]), Wfc[k0 + e], s);
    }
    red[tid] = s;
    __syncthreads();
    if (q == 0)
      out[gr * 64 + r] = red[tid] + red[tid + 1] + red[tid + 2] + red[tid + 3] + bfc[0];
  }
}

extern "C" void kernel_launch(void* const* d_in, const int* in_sizes, int n_in,
                              void* d_out, int out_size, void* d_ws, size_t ws_size,
                              hipStream_t stream)
{
  if (ws_size < WS_NEED) {
    fprintf(stderr, "kernel_launch: ws_size %zu < needed %zu\n", ws_size, WS_NEED);
    return;
  }
  const float* inp = (const float*)d_in[0];
  const float* Wx1 = (const float*)d_in[1];
  const float* Wh1 = (const float*)d_in[2];
  const float* b1  = (const float*)d_in[3];
  const float* Wx2 = (const float*)d_in[4];
  const float* Wh2 = (const float*)d_in[5];
  const float* b2  = (const float*)d_in[6];
  const float* Wfc = (const float*)d_in[7];
  const float* bfc = (const float*)d_in[8];
  unsigned char* ws = (unsigned char*)d_ws;

  hipMemsetAsync(ws, 0, 8192, stream);                        // flags
  pack_w<<<768, 256, 0, stream>>>(Wh1, Wh2, Wx2, ws);
  lstm_main<<<256, 256, 0, stream>>>(inp, Wx1, b1, b2, Wfc, bfc, ws, (float*)d_out);
}

// Round 11
// 1453.139 us; speedup vs baseline: 4.5948x; 1.1664x over previous
//
#include <hip/hip_runtime.h>
#include <cstdio>

typedef __attribute__((ext_vector_type(8))) short short8;
typedef __attribute__((ext_vector_type(4))) float f32x4;
typedef unsigned long long u64;

#define MFMA16(a,b,c) __builtin_amdgcn_mfma_f32_16x16x32_bf16((a),(b),(c),0,0,0)
#define LOAD_SYS(p)    __hip_atomic_load((p), __ATOMIC_RELAXED, __HIP_MEMORY_SCOPE_SYSTEM)
#define STORE_SYS(p,v) __hip_atomic_store((p), (v), __ATOMIC_RELAXED, __HIP_MEMORY_SCOPE_SYSTEM)

typedef __attribute__((address_space(1))) unsigned AS1U;
typedef __attribute__((address_space(3))) unsigned AS3U;

// workspace layout (bytes). 16 row-groups of 32 rows; tiles are 32KB.
constexpr size_t CNT_OFF = 0;                            // 16 groups * 32 flag words
constexpr size_t HB_OFF  = 8192;                         // 2 * 16 * 32KB = 1MB
constexpr size_t PK1_OFF = HB_OFF + 1048576;             // Wh1 pack, 2MB
constexpr size_t PK2_OFF = PK1_OFF + 2097152;            // Wh2 pack, 2MB
constexpr size_t PKX_OFF = PK2_OFF + 2097152;            // Wx2 pack, 2MB
constexpr size_t SEQ_OFF = PKX_OFF + 2097152;            // seq1: 16 * 200 * 32KB (~102MB)
constexpr size_t WS_NEED = SEQ_OFF + 16ul * 200 * 32768; // ~110 MB

__device__ __forceinline__ short f2bf(float f) {
  union { float f; unsigned u; } v; v.f = f;
  unsigned r = v.u + 0x7fffu + ((v.u >> 16) & 1u);
  return (short)(r >> 16);
}
__device__ __forceinline__ float bf2f(short s) {
  union { float f; unsigned u; } v; v.u = ((unsigned)(unsigned short)s) << 16;
  return v.f;
}
__device__ __forceinline__ float sigm(float x)   { return 1.f / (1.f + __expf(-x)); }
__device__ __forceinline__ float tanh_f(float x) { return 1.f - 2.f / (1.f + __expf(2.f * x)); }

// Pack W[512][2048] fp32 (K x N) into MFMA B-fragment order:
// frag (nf,kf): lane l, elem e holds B[k = kf*32 + (l>>4)*8 + e][n = nf*16 + (l&15)]
__global__ void pack_w(const float* __restrict__ wh1, const float* __restrict__ wh2,
                       const float* __restrict__ wx2, unsigned char* __restrict__ ws)
{
  int tid = blockIdx.x * 256 + threadIdx.x;   // 3 * 65536 threads
  int m   = tid >> 16;
  int rem = tid & 65535;
  int k   = rem >> 7;     // 0..511
  int nf  = rem & 127;    // 0..127
  const float* W = (m == 0) ? wh1 : (m == 1) ? wh2 : wx2;
  short* dst = (short*)(ws + ((m == 0) ? PK1_OFF : (m == 1) ? PK2_OFF : PKX_OFF));
  int kf = k >> 5, sub = (k >> 3) & 3, e = k & 7;
  int base = ((nf * 16 + kf) * 64 + sub * 16) * 8 + e;
  const float* src = W + (size_t)k * 2048 + nf * 16;
#pragma unroll
  for (int c = 0; c < 16; ++c) dst[base + c * 8] = f2bf(src[c]);
}

// 16 groups x 32 rows; 16 WGs/group, each owns h-cols [wj*32, wj*32+32) (x4 gates).
// Wave w: gates {2(w>>1), 2(w>>1)+1}, col-frag (w&1). A-tiles staged via global_load_lds.
__global__ __launch_bounds__(256, 1) void lstm_main(
    const float* __restrict__ inp, const float* __restrict__ Wx1,
    const float* __restrict__ b1,  const float* __restrict__ b2,
    const float* __restrict__ Wfc, const float* __restrict__ bfc,
    unsigned char* __restrict__ ws, float* __restrict__ out)
{
  __shared__ short8 ldsA[2048];              // seq tile, 32KB
  __shared__ short8 ldsB[2048];              // h2 tile, 32KB
  __shared__ short8 bwx[4][2][8][64];        // Wx2 kf<8 per wave, 64KB
  __shared__ float  zlds[32][132];           // pre-activation exchange, 16.5KB
  __shared__ unsigned short htile[32][36];   // h transpose staging, 2.25KB
  __shared__ float  red[256];

  const int tid  = threadIdx.x;
  const int blk  = blockIdx.x;
  const int gr   = blk & 15;    // row-group (32 rows)
  const int wj   = blk >> 4;    // 0..15: h-cols [wj*32, wj*32+32)
  const int w    = tid >> 6;
  const int lane = tid & 63;
  const int g0   = (w >> 1) << 1;   // this wave's gate pair
  const int cf   = w & 1;           // col-frag within the 32 h-cols

  unsigned* fl = (unsigned*)(ws + CNT_OFF) + gr * 32;   // 16 flags on one line
  short8* hb0p = (short8*)(ws + HB_OFF) + (size_t)(0 * 16 + gr) * 2048;
  short8* hb1p = (short8*)(ws + HB_OFF) + (size_t)(1 * 16 + gr) * 2048;
  const short8* pk1 = (const short8*)(ws + PK1_OFF);
  const short8* pk2 = (const short8*)(ws + PK2_OFF);
  const short8* pkx = (const short8*)(ws + PKX_OFF);
  short8* seq = (short8*)(ws + SEQ_OFF) + (size_t)gr * (200 * 2048);

  // B-fragments: Wh1, Wh2 fully in VGPRs; Wx2 kf<8 -> LDS, kf>=8 -> VGPRs
  short8 wh1f[2][16], wh2f[2][16], wxhi[2][8];
#pragma unroll
  for (int Gl = 0; Gl < 2; ++Gl) {
    int nf = (g0 + Gl) * 32 + wj * 2 + cf;
#pragma unroll
    for (int kf = 0; kf < 16; ++kf) {
      wh1f[Gl][kf] = pk1[(nf * 16 + kf) * 64 + lane];
      wh2f[Gl][kf] = pk2[(nf * 16 + kf) * 64 + lane];
    }
#pragma unroll
    for (int kf = 0; kf < 8; ++kf)
      bwx[w][Gl][kf][lane] = pkx[(nf * 16 + kf) * 64 + lane];
#pragma unroll
    for (int kf = 8; kf < 16; ++kf)
      wxhi[Gl][kf - 8] = pkx[(nf * 16 + kf) * 64 + lane];
  }

  // gate-thread mapping: hcol = tid&31, rows rq*4..+3
  const int hcol = tid & 31, rq = tid >> 5;
  const int jcol = wj * 32 + hcol;
  float wx1v[4], b1v[4], b2v[4];
#pragma unroll
  for (int G = 0; G < 4; ++G) {
    wx1v[G] = Wx1[G * 512 + jcol];
    b1v[G]  = b1[G * 512 + jcol];
    b2v[G]  = b2[G * 512 + jcol];
  }
  const float* xptr = inp + (size_t)(gr * 32 + rq * 4) * 200;

  // pack-thread mapping: row pr, 4 cols at pc0
  const int pr = tid >> 3, pq = tid & 7;
  const int pc0 = wj * 32 + pq * 4;
  const int bq = ((((pc0 >> 5) * 2 + (pr >> 4)) * 64 + ((pc0 >> 3) & 3) * 16 + (pr & 15)) * 8
                  + (pc0 & 7)) >> 2;   // u64 index into 32-row A-frag pack

  float cst1[4] = {0.f, 0.f, 0.f, 0.f};
  float cst2[4] = {0.f, 0.f, 0.f, 0.f};

  __syncthreads();   // bwx staged

#pragma unroll 1
  for (int s = 0; s <= 200; ++s) {
    float xv[4];
    if (s < 200) {
#pragma unroll
      for (int i = 0; i < 4; ++i) xv[i] = xptr[i * 200 + s];
    }

    if (s > 0) {
      if (tid < 64) {
        const unsigned* fp = &fl[tid & 15];
        while (1) {
          unsigned v = LOAD_SYS((unsigned*)fp);
          if (__all((int)(v >= (unsigned)s))) break;
          __builtin_amdgcn_s_sleep(1);
        }
        asm volatile("" ::: "memory");
      }
    }
    __syncthreads();   // (1) all waves gated; prior-step LDS reads complete

    // ---- merged async stage: seq[s-1] -> ldsA, h2_{s-2} -> ldsB (LLC-direct) ----
    if (s >= 1) {
      const char* gsrc = (const char*)(seq + (size_t)(s - 1) * 2048);
      char* ldst = (char*)ldsA;
#pragma unroll
      for (int i = 0; i < 8; ++i)
        __builtin_amdgcn_global_load_lds(
            (const AS1U*)(gsrc + (w * 8 + i) * 1024 + lane * 16),
            (AS3U*)(ldst + (w * 8 + i) * 1024), 16, 0, 17 /* sc0|sc1 */);
    }
    if (s >= 2) {
      const char* gsrc = (const char*)((s & 1) ? hb1p : hb0p);
      char* ldst = (char*)ldsB;
#pragma unroll
      for (int i = 0; i < 8; ++i)
        __builtin_amdgcn_global_load_lds(
            (const AS1U*)(gsrc + (w * 8 + i) * 1024 + lane * 16),
            (AS3U*)(ldst + (w * 8 + i) * 1024), 16, 0, 17);
    }
    __builtin_amdgcn_sched_barrier(0);
    if (s >= 2) asm volatile("s_waitcnt vmcnt(8)" ::: "memory");   // seq done, hb in flight
    else        asm volatile("s_waitcnt vmcnt(0)" ::: "memory");
    __builtin_amdgcn_sched_barrier(0);
    __builtin_amdgcn_s_barrier();   // (2) ldsA ready for all waves

    f32x4 acc1[2][2], acc2[2][2];
#pragma unroll
    for (int Gl = 0; Gl < 2; ++Gl)
#pragma unroll
      for (int m = 0; m < 2; ++m) {
        f32x4 z = {0.f, 0.f, 0.f, 0.f}; acc1[Gl][m] = z; acc2[Gl][m] = z;
      }

    // ---- L1 recurrent + L2 x-projection: both consume ldsA ----
    if (s >= 1) {
#pragma unroll
      for (int m = 0; m < 2; ++m) {
#pragma unroll
        for (int kf = 0; kf < 16; ++kf) {
          short8 a = ldsA[(kf * 2 + m) * 64 + lane];
#pragma unroll
          for (int Gl = 0; Gl < 2; ++Gl) {
            if (s < 200) acc1[Gl][m] = MFMA16(a, wh1f[Gl][kf], acc1[Gl][m]);
            short8 bx = (kf < 8) ? bwx[w][Gl][kf][lane] : wxhi[Gl][kf - 8];
            acc2[Gl][m] = MFMA16(a, bx, acc2[Gl][m]);
          }
        }
      }
    }

    // ---- L1 pre-acts -> zlds (s==0: zeros) ----
    if (s < 200) {
#pragma unroll
      for (int Gl = 0; Gl < 2; ++Gl)
#pragma unroll
        for (int m = 0; m < 2; ++m)
#pragma unroll
          for (int r = 0; r < 4; ++r)
            zlds[m * 16 + (lane >> 4) * 4 + r][(g0 + Gl) * 32 + cf * 16 + (lane & 15)]
                = acc1[Gl][m][r];
    }
    __syncthreads();   // (3) zlds(L1) ready; ldsB ready (vmcnt drained)

    // ---- L1 gates ----
    if (s < 200) {
#pragma unroll
      for (int i = 0; i < 4; ++i) {
        int row = rq * 4 + i;
        float zi = zlds[row][0 * 32 + hcol] + fmaf(xv[i], wx1v[0], b1v[0]);
        float zf = zlds[row][1 * 32 + hcol] + fmaf(xv[i], wx1v[1], b1v[1]);
        float zg = zlds[row][2 * 32 + hcol] + fmaf(xv[i], wx1v[2], b1v[2]);
        float zo = zlds[row][3 * 32 + hcol] + fmaf(xv[i], wx1v[3], b1v[3]);
        float cc = sigm(zf) * cst1[i] + sigm(zi) * tanh_f(zg);
        cst1[i] = cc;
        htile[row][hcol] = (unsigned short)f2bf(sigm(zo) * tanh_f(cc));
      }
    }

    // ---- L2 recurrent from ldsB ----
    if (s >= 2) {
#pragma unroll
      for (int m = 0; m < 2; ++m) {
#pragma unroll
        for (int kf = 0; kf < 16; ++kf) {
          short8 a = ldsB[(kf * 2 + m) * 64 + lane];
#pragma unroll
          for (int Gl = 0; Gl < 2; ++Gl)
            acc2[Gl][m] = MFMA16(a, wh2f[Gl][kf], acc2[Gl][m]);
        }
      }
    }
    __syncthreads();   // (4) htile(L1) ready; zlds free

    if (s < 200) {
      u64 hv = *(const u64*)&htile[pr][pq * 4];
      STORE_SYS((u64*)(seq + (size_t)s * 2048) + bq, hv);
    }

    // ---- L2 pre-acts -> zlds ----
    if (s >= 1) {
#pragma unroll
      for (int Gl = 0; Gl < 2; ++Gl)
#pragma unroll
        for (int m = 0; m < 2; ++m)
#pragma unroll
          for (int r = 0; r < 4; ++r)
            zlds[m * 16 + (lane >> 4) * 4 + r][(g0 + Gl) * 32 + cf * 16 + (lane & 15)]
                = acc2[Gl][m][r];
    }
    __syncthreads();   // (5) zlds(L2) ready; htile(L1) consumed

    // ---- L2 gates ----
    if (s >= 1) {
#pragma unroll
      for (int i = 0; i < 4; ++i) {
        int row = rq * 4 + i;
        float zi = zlds[row][0 * 32 + hcol] + b2v[0];
        float zf = zlds[row][1 * 32 + hcol] + b2v[1];
        float zg = zlds[row][2 * 32 + hcol] + b2v[2];
        float zo = zlds[row][3 * 32 + hcol] + b2v[3];
        float cc = sigm(zf) * cst2[i] + sigm(zi) * tanh_f(zg);
        cst2[i] = cc;
        htile[row][hcol] = (unsigned short)f2bf(sigm(zo) * tanh_f(cc));
      }
    }
    __syncthreads();   // (6) htile(L2) ready

    if (s >= 1) {
      u64 hv = *(const u64*)&htile[pr][pq * 4];
      short8* dst = (s & 1) ? hb0p : hb1p;   // hb[(s+1)&1]
      STORE_SYS((u64*)dst + bq, hv);
    }
    __syncthreads();   // (7) stores drained (vmcnt 0) before post
    if (tid == 0)
      STORE_SYS(&fl[wj], (unsigned)(s + 1));
  }

  // final FC: logits = h2_199 @ Wfc + bfc  (s=200 wrote hb1)
  if (wj == 0) {
    if (tid < 64) {
      const unsigned* fp = &fl[tid & 15];
      while (1) {
        unsigned v = LOAD_SYS((unsigned*)fp);
        if (__all((int)(v >= 201u))) break;
        __builtin_amdgcn_s_sleep(1);
      }
      asm volatile("" ::: "memory");
    }
    __syncthreads();

    const u64* h2 = (const u64*)hb1p;
    int r = tid >> 3, q = tid & 7;
    float sum = 0.f;
#pragma unroll
    for (int c = 0; c < 8; ++c) {
      int k0 = q * 64 + c * 8;
      int kf = k0 >> 5, sub = (k0 >> 3) & 3, m = r >> 4;
      int bq2 = ((kf * 2 + m) * 64 + sub * 16 + (r & 15)) * 2;
      union { u64 u[2]; unsigned short ss[8]; } cv;
      cv.u[0] = LOAD_SYS((u64*)h2 + bq2);
      cv.u[1] = LOAD_SYS((u64*)h2 + bq2 + 1);
#pragma unroll
      for (int e = 0; e < 8; ++e)
        sum = fmaf(bf2f((short)cv.ss[e]), Wfc[k0 + e], sum);
    }
    red[tid] = sum;
    __syncthreads();
    if (q == 0) {
      float o = bfc[0];
#pragma unroll
      for (int j = 0; j < 8; ++j) o += red[r * 8 + j];
      out[gr * 32 + r] = o;
    }
  }
}

extern "C" void kernel_launch(void* const* d_in, const int* in_sizes, int n_in,
                              void* d_out, int out_size, void* d_ws, size_t ws_size,
                              hipStream_t stream)
{
  if (ws_size < WS_NEED) {
    fprintf(stderr, "kernel_launch: ws_size %zu < needed %zu\n", ws_size, WS_NEED);
    return;
  }
  const float* inp = (const float*)d_in[0];
  const float* Wx1 = (const float*)d_in[1];
  const float* Wh1 = (const float*)d_in[2];
  const float* b1  = (const float*)d_in[3];
  const float* Wx2 = (const float*)d_in[4];
  const float* Wh2 = (const float*)d_in[5];
  const float* b2  = (const float*)d_in[6];
  const float* Wfc = (const float*)d_in[7];
  const float* bfc = (const float*)d_in[8];
  unsigned char* ws = (unsigned char*)d_ws;

  hipMemsetAsync(ws, 0, 8192, stream);                        // flags
  pack_w<<<768, 256, 0, stream>>>(Wh1, Wh2, Wx2, ws);
  lstm_main<<<256, 256, 0, stream>>>(inp, Wx1, b1, b2, Wfc, bfc, ws, (float*)d_out);
}